// Round 9
// baseline (145.910 us; speedup 1.0000x reference)
//
#include <hip/hip_runtime.h>
#include <float.h>
#include <math.h>

#define SCORE_TH 0.05f
#define IOU_TH   0.5f
#define MAXD     100
#define CAP      512       // per-class candidate buffer (E[n]=200, sigma=14 -> 22 sigma margin)
#define HI_TH    0.996f    // P(uniform^4 > 0.996) ~ 1.0e-3 -> ~200 cand/class
#define SWALK    192       // sorted prefix examined (need ~110 to keep 100); 3 u64 words
#define NWORDS   3
#define CNT_STRIDE 16      // pad class counters to one 64B line each (atomic line-parallelism)

// Inline RetinaNet decode + clip (identical arithmetic to the originally verified k_decode)
__device__ __forceinline__ float4 decode_box(float4 an, float4 r, float W, float H)
{
    float wa = an.z - an.x, ha = an.w - an.y;
    float cxa = an.x + 0.5f * wa, cya = an.y + 0.5f * ha;
    float cx = cxa + r.x * 0.1f * wa;
    float cy = cya + r.y * 0.1f * ha;
    float w  = expf(r.z * 0.2f) * wa;
    float h  = expf(r.w * 0.2f) * ha;
    float x1 = cx - 0.5f * w, y1 = cy - 0.5f * h;
    float x2 = cx + 0.5f * w, y2 = cy + 0.5f * h;
    x1 = fminf(fmaxf(x1, 0.f), W);
    y1 = fminf(fmaxf(y1, 0.f), H);
    x2 = fminf(fmaxf(x2, 0.f), W);
    y2 = fminf(fmaxf(y2, 0.f), H);
    return make_float4(x1, y1, x2, y2);
}

// ---------------- K2: grid-stride candidate compaction (dominant kernel: 64MB scan) ----------------
// CC>0: compile-time class count (strength-reduced div/mod). CC==0: generic runtime path.
template<int CC>
__global__ __launch_bounds__(256)
void k_compact(const float4* __restrict__ cls4, float2* __restrict__ cand,
               int* __restrict__ cnt, int* __restrict__ loflag,
               int C_rt, int total4)
{
    const int C = CC ? CC : C_rt;
    __shared__ unsigned char lflag[256];   // C <= 256 assumed (C=80 here)
    for (int i = threadIdx.x; i < C; i += blockDim.x) lflag[i] = 0;
    __syncthreads();

    const int gstride = gridDim.x * blockDim.x;
    const int gtid = blockIdx.x * blockDim.x + threadIdx.x;

    for (int j0 = gtid; j0 < total4; j0 += 4 * gstride) {
        int j1 = j0 + gstride, j2 = j0 + 2 * gstride, j3 = j0 + 3 * gstride;
        bool ok1 = j1 < total4, ok2 = j2 < total4, ok3 = j3 < total4;
        // 4 independent coalesced 16B loads in flight
        float4 v0 = cls4[j0];
        float4 v1 = ok1 ? cls4[j1] : make_float4(0.f, 0.f, 0.f, 0.f);
        float4 v2 = ok2 ? cls4[j2] : make_float4(0.f, 0.f, 0.f, 0.f);
        float4 v3 = ok3 ? cls4[j3] : make_float4(0.f, 0.f, 0.f, 0.f);

        #pragma unroll
        for (int w = 0; w < 4; w++) {
            float4 v = (w == 0) ? v0 : (w == 1) ? v1 : (w == 2) ? v2 : v3;
            if (w == 1 && !ok1) break;
            if (w == 2 && !ok2) break;
            if (w == 3 && !ok3) break;
            unsigned b = (unsigned)(j0 + w * gstride) * 4u;   // flat element index (<2^31)
            int c = (int)(b % (unsigned)C);
            int a = (int)(b / (unsigned)C);
            float s[4] = {v.x, v.y, v.z, v.w};
            #pragma unroll
            for (int j = 0; j < 4; j++) {
                float sc = s[j];
                if (sc > HI_TH) {
                    int pos = atomicAdd(&cnt[c * CNT_STRIDE], 1);
                    if (pos < CAP) cand[(size_t)c * CAP + pos] = make_float2(sc, __int_as_float(a));
                } else if (sc > SCORE_TH) {
                    lflag[c] = 1;           // racy idempotent byte write: fine
                }
                c++; if (c == C) { c = 0; a++; }
            }
        }
    }
    __syncthreads();
    for (int i = threadIdx.x; i < C; i += blockDim.x)
        if (lflag[i]) loflag[i] = 1;        // plain store of 1: idempotent
}

// ---------------- K3: sort + parallel-mask + bitset-resolve exact NMS per class ----------------
// Greedy NMS decomposed: (a) sort by (score desc, anchor asc); (b) PARALLEL all-pairs
// IoU bitmask over the top SWALK; (c) tiny serial bitset resolve (torchvision-style):
// k kept iff its bit unset; kept rows OR their suppression word-row. Exactly greedy.
__global__ __launch_bounds__(256)
void k_nms(const float4* __restrict__ anch, const float4* __restrict__ reg,
           const int* __restrict__ ph, const int* __restrict__ pw,
           const float2* __restrict__ cand, const int* __restrict__ cnt,
           const int* __restrict__ loflag, int* __restrict__ incomp,
           float* __restrict__ out, int C)
{
    int c = blockIdx.x;
    __shared__ unsigned long long keys[CAP];       // ascending key = best first
    __shared__ float bx1[SWALK], by1[SWALK], bx2[SWALK], by2[SWALK], sar[SWALK];
    __shared__ unsigned long long mask[SWALK][NWORDS];   // bit j of mask[i]: IoU(i,j)>th, j>i
    __shared__ int kidx[MAXD];

    int n_raw = cnt[c * CNT_STRIDE];
    if (n_raw > CAP) {                   // lost candidates -> exact fallback (uniform early return)
        if (threadIdx.x == 0) incomp[c] = 1;
        return;
    }
    int n = n_raw;

    // load + pack keys: ascending order == descending score, tie -> ascending anchor id
    for (int i = threadIdx.x; i < CAP; i += blockDim.x) {
        if (i < n) {
            float2 e = cand[(size_t)c * CAP + i];
            unsigned sbits = __float_as_uint(e.x);          // score > 0 -> bits monotone
            unsigned aid   = (unsigned)__float_as_int(e.y); // anchor id
            keys[i] = ((unsigned long long)(~sbits) << 32) | (unsigned long long)aid;
        } else {
            keys[i] = 0xFFFFFFFFFFFFFFFFull;                // pad sorts last
        }
    }
    __syncthreads();

    // adaptive ascending bitonic sort: 256-wide network when n fits (common case),
    // else full 512. Downstream only reads keys[0..min(n,SWALK)).
    const int SORTN = (n <= 256) ? 256 : CAP;
    for (int k = 2; k <= SORTN; k <<= 1) {
        for (int j = k >> 1; j > 0; j >>= 1) {
            for (int i = threadIdx.x; i < SORTN; i += blockDim.x) {
                int ixj = i ^ j;
                if (ixj > i) {
                    unsigned long long a = keys[i], b = keys[ixj];
                    bool sw = ((i & k) == 0) ? (a > b) : (a < b);
                    if (sw) { keys[i] = b; keys[ixj] = a; }
                }
            }
            __syncthreads();
        }
    }

    // stage sorted prefix: gather anchors+regression, decode inline
    float W = (float)(*pw), H = (float)(*ph);
    int nS = n < SWALK ? n : SWALK;
    for (int i = threadIdx.x; i < nS; i += blockDim.x) {
        unsigned aid = (unsigned)keys[i];
        float4 b = decode_box(anch[aid], reg[aid], W, H);
        bx1[i] = b.x; by1[i] = b.y; bx2[i] = b.z; by2[i] = b.w;
        sar[i] = (b.z - b.x) * (b.w - b.y);
    }
    __syncthreads();

    // parallel suppression-mask build: task = (row i, word w); bit j (> i) set if IoU>th
    for (int task = threadIdx.x; task < nS * NWORDS; task += blockDim.x) {
        int i = task / NWORDS;
        int w = task - i * NWORDS;
        unsigned long long m = 0ull;
        int j0 = w << 6;
        int jend = j0 + 64 < nS ? j0 + 64 : nS;
        int js = j0 > i + 1 ? j0 : i + 1;
        float ix1 = bx1[i], iy1 = by1[i], ix2 = bx2[i], iy2 = by2[i], ia = sar[i];
        for (int j = js; j < jend; ++j) {
            float xx1 = fmaxf(ix1, bx1[j]);
            float yy1 = fmaxf(iy1, by1[j]);
            float xx2 = fminf(ix2, bx2[j]);
            float yy2 = fminf(iy2, by2[j]);
            float inter = fmaxf(xx2 - xx1, 0.f) * fmaxf(yy2 - yy1, 0.f);
            float iou = inter / (ia + sar[j] - inter);      // NaN -> false, matches JAX
            if (iou > IOU_TH) m |= 1ull << (j - j0);
        }
        mask[i][w] = m;
    }
    __syncthreads();

    // serial bitset resolve, run redundantly by all threads in lockstep (LDS broadcasts,
    // loads unconditional -> compiler pipelines them past the dependent OR chain)
    unsigned long long rem0 = 0, rem1 = 0, rem2 = 0;
    int kept = 0;
    for (int k = 0; k < nS && kept < MAXD; ++k) {
        unsigned long long m0 = mask[k][0], m1 = mask[k][1], m2 = mask[k][2];
        unsigned long long rw = (k < 64) ? rem0 : (k < 128) ? rem1 : rem2;
        if (!((rw >> (k & 63)) & 1ull)) {
            if (threadIdx.x == 0) kidx[kept] = k;
            ++kept;
            rem0 |= m0; rem1 |= m1; rem2 |= m2;
        }
    }
    __syncthreads();   // kidx visible

    if (kept < MAXD && (n > nS || loflag[c] != 0)) {   // unexamined candidates may exist
        if (threadIdx.x == 0) incomp[c] = 1;           // -> exact fallback owns this class
        return;
    }

    int total = C * MAXD;
    int base = c * MAXD;
    for (int m = threadIdx.x; m < kept; m += blockDim.x) {
        int k = kidx[m];
        unsigned long long key = keys[k];
        float sc = __uint_as_float(~(unsigned)(key >> 32));
        out[base + m] = sc;
        out[total + base + m] = (float)c;
        float* ob = out + 2 * (size_t)total + (size_t)(base + m) * 4;
        ob[0] = bx1[k]; ob[1] = by1[k]; ob[2] = bx2[k]; ob[3] = by2[k];
    }
    for (int m = kept + threadIdx.x; m < MAXD; m += blockDim.x) {
        out[base + m] = 0.f;
        out[total + base + m] = -1.f;
        float* ob = out + 2 * (size_t)total + (size_t)(base + m) * 4;
        ob[0] = 0.f; ob[1] = 0.f; ob[2] = 0.f; ob[3] = 0.f;
    }
}

// ---------------- K4: exact fallback (lazy sorted-order walk over all A; statistically never fires) ----------------
__global__ __launch_bounds__(256)
void k_fallback(const float* __restrict__ cls,
                const float4* __restrict__ anch, const float4* __restrict__ reg,
                const int* __restrict__ ph, const int* __restrict__ pw,
                const int* __restrict__ incomp, float* __restrict__ out,
                int A, int C)
{
    int c = blockIdx.x;
    if (!incomp[c]) return;
    __shared__ float kx1[MAXD], ky1[MAXD], kx2[MAXD], ky2[MAXD], kar[MAXD];
    __shared__ float rs[4]; __shared__ int ra[4];
    __shared__ float cs; __shared__ int caid; __shared__ int have; __shared__ int suppflag;
    int lane = threadIdx.x & 63, wid = threadIdx.x >> 6;
    float W = (float)(*pw), H = (float)(*ph);
    float s_last = FLT_MAX; int a_last = -1;
    int kept = 0;
    int total = C * MAXD;
    for (long long guard = 0; guard <= (long long)A && kept < MAXD; guard++) {
        // next candidate strictly after (s_last, a_last) in descending (score, -idx) order
        float bs = -1.f; int ba = 0x7fffffff;
        for (int a = threadIdx.x; a < A; a += blockDim.x) {
            float s = cls[(size_t)a * C + c];
            if (s <= SCORE_TH) continue;
            if (s > s_last || (s == s_last && a <= a_last)) continue;  // already examined
            if (s > bs || (s == bs && a < ba)) { bs = s; ba = a; }
        }
        for (int off = 32; off >= 1; off >>= 1) {
            float s2 = __shfl_down(bs, off);
            int a2 = __shfl_down(ba, off);
            if (s2 > bs || (s2 == bs && a2 < ba)) { bs = s2; ba = a2; }
        }
        if (lane == 0) { rs[wid] = bs; ra[wid] = ba; }
        __syncthreads();
        if (threadIdx.x == 0) {
            float fs = rs[0]; int fa = ra[0];
            for (int w = 1; w < 4; w++)
                if (rs[w] > fs || (rs[w] == fs && ra[w] < fa)) { fs = rs[w]; fa = ra[w]; }
            cs = fs; caid = fa; have = (fs > 0.f) ? 1 : 0;
        }
        __syncthreads();
        if (!have) break;
        float s_c = cs; int a_c = caid;
        s_last = s_c; a_last = a_c;
        float4 b = decode_box(anch[a_c], reg[a_c], W, H);   // inline decode (redundant per thread, cheap)
        float ar = (b.z - b.x) * (b.w - b.y);
        if (threadIdx.x == 0) suppflag = 0;
        __syncthreads();
        for (int k = threadIdx.x; k < kept; k += blockDim.x) {
            float xx1 = fmaxf(b.x, kx1[k]);
            float yy1 = fmaxf(b.y, ky1[k]);
            float xx2 = fminf(b.z, kx2[k]);
            float yy2 = fminf(b.w, ky2[k]);
            float inter = fmaxf(xx2 - xx1, 0.f) * fmaxf(yy2 - yy1, 0.f);
            float iou = inter / (ar + kar[k] - inter);
            if (iou > IOU_TH) suppflag = 1;  // racy idempotent
        }
        __syncthreads();
        if (!suppflag) {
            if (threadIdx.x == 0) {
                kx1[kept] = b.x; ky1[kept] = b.y; kx2[kept] = b.z; ky2[kept] = b.w; kar[kept] = ar;
                int slot = c * MAXD + kept;
                out[slot] = s_c;
                out[total + slot] = (float)c;
                float* ob = out + 2 * (size_t)total + (size_t)slot * 4;
                ob[0] = b.x; ob[1] = b.y; ob[2] = b.z; ob[3] = b.w;
            }
            kept++;
        }
        __syncthreads();
    }
    for (int k = kept + threadIdx.x; k < MAXD; k += blockDim.x) {
        int slot = c * MAXD + k;
        out[slot] = 0.f;
        out[total + slot] = -1.f;
        float* ob = out + 2 * (size_t)total + (size_t)slot * 4;
        ob[0] = 0.f; ob[1] = 0.f; ob[2] = 0.f; ob[3] = 0.f;
    }
}

extern "C" void kernel_launch(void* const* d_in, const int* in_sizes, int n_in,
                              void* d_out, int out_size, void* d_ws, size_t ws_size,
                              hipStream_t stream)
{
    const float*  cls  = (const float*)d_in[0];
    const float4* reg  = (const float4*)d_in[1];
    const float4* anch = (const float4*)d_in[2];
    const int*    ph   = (const int*)d_in[3];
    const int*    pw   = (const int*)d_in[4];
    int A = in_sizes[1] / 4;
    int C = in_sizes[0] / A;
    float* out = (float*)d_out;

    char* ws = (char*)d_ws;
    float2* cand = (float2*)ws;                        // C*CAP * 8B
    int* ctrl   = (int*)(cand + (size_t)C * CAP);      // cnt_pad[C*16] | loflag[C] | incomp[C]
    int* cnt    = ctrl;                                // strided by CNT_STRIDE
    int* loflag = ctrl + C * CNT_STRIDE;
    int* incomp = loflag + C;

    hipMemsetAsync(ctrl, 0, (C * CNT_STRIDE + 2 * C) * sizeof(int), stream);

    int total4 = (int)((long long)A * C / 4);
    int blocks2 = (total4 + 255) / 256;
    if (blocks2 > 2048) blocks2 = 2048;
    if (C == 80 && (long long)A * C < (1LL << 31))
        k_compact<80><<<blocks2, 256, 0, stream>>>((const float4*)cls, cand, cnt, loflag, C, total4);
    else
        k_compact<0><<<blocks2, 256, 0, stream>>>((const float4*)cls, cand, cnt, loflag, C, total4);

    k_nms<<<C, 256, 0, stream>>>(anch, reg, ph, pw, cand, cnt, loflag, incomp, out, C);
    k_fallback<<<C, 256, 0, stream>>>(cls, anch, reg, ph, pw, incomp, out, A, C);
}

// Round 11
// 140.297 us; speedup vs baseline: 1.0400x; 1.0400x over previous
//
#include <hip/hip_runtime.h>
#include <float.h>
#include <math.h>

#define SCORE_TH 0.05f
#define IOU_TH   0.5f
#define MAXD     100
#define CAP      512       // per-class candidate buffer (E[n]=200, sigma=14 -> 22 sigma margin)
#define HI_TH    0.996f    // P(uniform^4 > 0.996) ~ 1.0e-3 -> ~200 cand/class
#define SWALK    192       // sorted prefix examined (multiple of 4; need ~110 to keep 100)
#define NWORDS   3
#define CNT_STRIDE 16      // pad class counters to one 64B line each (atomic line-parallelism)

// Inline RetinaNet decode + clip (identical arithmetic to the originally verified k_decode)
__device__ __forceinline__ float4 decode_box(float4 an, float4 r, float W, float H)
{
    float wa = an.z - an.x, ha = an.w - an.y;
    float cxa = an.x + 0.5f * wa, cya = an.y + 0.5f * ha;
    float cx = cxa + r.x * 0.1f * wa;
    float cy = cya + r.y * 0.1f * ha;
    float w  = expf(r.z * 0.2f) * wa;
    float h  = expf(r.w * 0.2f) * ha;
    float x1 = cx - 0.5f * w, y1 = cy - 0.5f * h;
    float x2 = cx + 0.5f * w, y2 = cy + 0.5f * h;
    x1 = fminf(fmaxf(x1, 0.f), W);
    y1 = fminf(fmaxf(y1, 0.f), H);
    x2 = fminf(fmaxf(x2, 0.f), W);
    y2 = fminf(fmaxf(y2, 0.f), H);
    return make_float4(x1, y1, x2, y2);
}

// ---------------- K2: grid-stride candidate compaction (dominant kernel: 64MB scan) ----------------
template<int CC>
__global__ __launch_bounds__(256)
void k_compact(const float4* __restrict__ cls4, float2* __restrict__ cand,
               int* __restrict__ cnt, int* __restrict__ loflag,
               int C_rt, int total4)
{
    const int C = CC ? CC : C_rt;
    __shared__ unsigned char lflag[256];   // C <= 256 assumed (C=80 here)
    for (int i = threadIdx.x; i < C; i += blockDim.x) lflag[i] = 0;
    __syncthreads();

    const int gstride = gridDim.x * blockDim.x;
    const int gtid = blockIdx.x * blockDim.x + threadIdx.x;

    for (int j0 = gtid; j0 < total4; j0 += 4 * gstride) {
        int j1 = j0 + gstride, j2 = j0 + 2 * gstride, j3 = j0 + 3 * gstride;
        bool ok1 = j1 < total4, ok2 = j2 < total4, ok3 = j3 < total4;
        float4 v0 = cls4[j0];
        float4 v1 = ok1 ? cls4[j1] : make_float4(0.f, 0.f, 0.f, 0.f);
        float4 v2 = ok2 ? cls4[j2] : make_float4(0.f, 0.f, 0.f, 0.f);
        float4 v3 = ok3 ? cls4[j3] : make_float4(0.f, 0.f, 0.f, 0.f);

        #pragma unroll
        for (int w = 0; w < 4; w++) {
            float4 v = (w == 0) ? v0 : (w == 1) ? v1 : (w == 2) ? v2 : v3;
            if (w == 1 && !ok1) break;
            if (w == 2 && !ok2) break;
            if (w == 3 && !ok3) break;
            unsigned b = (unsigned)(j0 + w * gstride) * 4u;   // flat element index (<2^31)
            int c = (int)(b % (unsigned)C);
            int a = (int)(b / (unsigned)C);
            float s[4] = {v.x, v.y, v.z, v.w};
            #pragma unroll
            for (int j = 0; j < 4; j++) {
                float sc = s[j];
                if (sc > HI_TH) {
                    int pos = atomicAdd(&cnt[c * CNT_STRIDE], 1);
                    if (pos < CAP) cand[(size_t)c * CAP + pos] = make_float2(sc, __int_as_float(a));
                } else if (sc > SCORE_TH) {
                    lflag[c] = 1;
                }
                c++; if (c == C) { c = 0; a++; }
            }
        }
    }
    __syncthreads();
    for (int i = threadIdx.x; i < C; i += blockDim.x)
        if (lflag[i]) loflag[i] = 1;
}

// ---------------- inline exact fallback (lazy sorted-order walk over all A) ----------------
// Runs per-class inside k_nms when the candidate prefix can't decide. Statistically never.
__device__ void fallback_class(const float* __restrict__ cls,
                               const float4* __restrict__ anch, const float4* __restrict__ reg,
                               float W, float H, int A, int C, int c,
                               float* __restrict__ out)
{
    __shared__ float kx1[MAXD], ky1[MAXD], kx2[MAXD], ky2[MAXD], kar[MAXD];
    __shared__ float rs[4]; __shared__ int ra[4];
    __shared__ float cs; __shared__ int caid; __shared__ int have; __shared__ int suppflag;
    int lane = threadIdx.x & 63, wid = threadIdx.x >> 6;
    float s_last = FLT_MAX; int a_last = -1;
    int kept = 0;
    int total = C * MAXD;
    for (long long guard = 0; guard <= (long long)A && kept < MAXD; guard++) {
        float bs = -1.f; int ba = 0x7fffffff;
        for (int a = threadIdx.x; a < A; a += blockDim.x) {
            float s = cls[(size_t)a * C + c];
            if (s <= SCORE_TH) continue;
            if (s > s_last || (s == s_last && a <= a_last)) continue;  // already examined
            if (s > bs || (s == bs && a < ba)) { bs = s; ba = a; }
        }
        for (int off = 32; off >= 1; off >>= 1) {
            float s2 = __shfl_down(bs, off);
            int a2 = __shfl_down(ba, off);
            if (s2 > bs || (s2 == bs && a2 < ba)) { bs = s2; ba = a2; }
        }
        if (lane == 0) { rs[wid] = bs; ra[wid] = ba; }
        __syncthreads();
        if (threadIdx.x == 0) {
            float fs = rs[0]; int fa = ra[0];
            for (int w = 1; w < 4; w++)
                if (rs[w] > fs || (rs[w] == fs && ra[w] < fa)) { fs = rs[w]; fa = ra[w]; }
            cs = fs; caid = fa; have = (fs > 0.f) ? 1 : 0;
        }
        __syncthreads();
        if (!have) break;
        float s_c = cs; int a_c = caid;
        s_last = s_c; a_last = a_c;
        float4 b = decode_box(anch[a_c], reg[a_c], W, H);
        float ar = (b.z - b.x) * (b.w - b.y);
        if (threadIdx.x == 0) suppflag = 0;
        __syncthreads();
        for (int k = threadIdx.x; k < kept; k += blockDim.x) {
            float xx1 = fmaxf(b.x, kx1[k]);
            float yy1 = fmaxf(b.y, ky1[k]);
            float xx2 = fminf(b.z, kx2[k]);
            float yy2 = fminf(b.w, ky2[k]);
            float inter = fmaxf(xx2 - xx1, 0.f) * fmaxf(yy2 - yy1, 0.f);
            float iou = inter / (ar + kar[k] - inter);
            if (iou > IOU_TH) suppflag = 1;  // racy idempotent
        }
        __syncthreads();
        if (!suppflag) {
            if (threadIdx.x == 0) {
                kx1[kept] = b.x; ky1[kept] = b.y; kx2[kept] = b.z; ky2[kept] = b.w; kar[kept] = ar;
                int slot = c * MAXD + kept;
                out[slot] = s_c;
                out[total + slot] = (float)c;
                float* ob = out + 2 * (size_t)total + (size_t)slot * 4;
                ob[0] = b.x; ob[1] = b.y; ob[2] = b.z; ob[3] = b.w;
            }
            kept++;
        }
        __syncthreads();
    }
    for (int k = kept + threadIdx.x; k < MAXD; k += blockDim.x) {
        int slot = c * MAXD + k;
        out[slot] = 0.f;
        out[total + slot] = -1.f;
        float* ob = out + 2 * (size_t)total + (size_t)slot * 4;
        ob[0] = 0.f; ob[1] = 0.f; ob[2] = 0.f; ob[3] = 0.f;
    }
}

// ---------------- K3: sort + parallel-mask + fast bitset-resolve + inline fallback ----------------
__global__ __launch_bounds__(256)
void k_nms(const float* __restrict__ cls,
           const float4* __restrict__ anch, const float4* __restrict__ reg,
           const int* __restrict__ ph, const int* __restrict__ pw,
           const float2* __restrict__ cand, const int* __restrict__ cnt,
           const int* __restrict__ loflag,
           float* __restrict__ out, int A, int C)
{
    int c = blockIdx.x;
    __shared__ unsigned long long keys[CAP];       // ascending key = best first
    __shared__ float bx1[SWALK], by1[SWALK], bx2[SWALK], by2[SWALK], sar[SWALK];
    __shared__ __align__(16) unsigned long long m0[SWALK], m1[SWALK], m2[SWALK]; // word-planes
    __shared__ int kidx[MAXD];

    float W = (float)(*pw), H = (float)(*ph);
    int n_raw = cnt[c * CNT_STRIDE];
    if (n_raw > CAP) {                   // lost candidates -> exact fallback, inline
        fallback_class(cls, anch, reg, W, H, A, C, c, out);
        return;
    }
    int n = n_raw;

    // adaptive sort width; init keys only in the sorted window
    const int SORTN = (n <= 256) ? 256 : CAP;
    for (int i = threadIdx.x; i < SORTN; i += blockDim.x) {
        if (i < n) {
            float2 e = cand[(size_t)c * CAP + i];
            unsigned sbits = __float_as_uint(e.x);          // score > 0 -> bits monotone
            unsigned aid   = (unsigned)__float_as_int(e.y); // anchor id
            keys[i] = ((unsigned long long)(~sbits) << 32) | (unsigned long long)aid;
        } else {
            keys[i] = 0xFFFFFFFFFFFFFFFFull;                // pad sorts last
        }
    }
    __syncthreads();

    // ascending bitonic sort (asc key == desc score, tie asc anchor id)
    for (int k = 2; k <= SORTN; k <<= 1) {
        for (int j = k >> 1; j > 0; j >>= 1) {
            for (int i = threadIdx.x; i < SORTN; i += blockDim.x) {
                int ixj = i ^ j;
                if (ixj > i) {
                    unsigned long long a = keys[i], b = keys[ixj];
                    bool sw = ((i & k) == 0) ? (a > b) : (a < b);
                    if (sw) { keys[i] = b; keys[ixj] = a; }
                }
            }
            __syncthreads();
        }
    }

    // stage sorted prefix: gather anchors+regression, decode inline
    int nS = n < SWALK ? n : SWALK;
    for (int i = threadIdx.x; i < nS; i += blockDim.x) {
        unsigned aid = (unsigned)keys[i];
        float4 b = decode_box(anch[aid], reg[aid], W, H);
        bx1[i] = b.x; by1[i] = b.y; bx2[i] = b.z; by2[i] = b.w;
        sar[i] = (b.z - b.x) * (b.w - b.y);
    }
    __syncthreads();

    // parallel suppression-mask build: task=(row i, word w); bit j (>i) set if IoU>th
    for (int task = threadIdx.x; task < nS * NWORDS; task += blockDim.x) {
        int i = task / NWORDS;
        int w = task - i * NWORDS;
        unsigned long long m = 0ull;
        int j0 = w << 6;
        int jend = j0 + 64 < nS ? j0 + 64 : nS;
        int js = j0 > i + 1 ? j0 : i + 1;
        float ix1 = bx1[i], iy1 = by1[i], ix2 = bx2[i], iy2 = by2[i], ia = sar[i];
        for (int j = js; j < jend; ++j) {
            float xx1 = fmaxf(ix1, bx1[j]);
            float yy1 = fmaxf(iy1, by1[j]);
            float xx2 = fminf(ix2, bx2[j]);
            float yy2 = fminf(iy2, by2[j]);
            float inter = fmaxf(xx2 - xx1, 0.f) * fmaxf(yy2 - yy1, 0.f);
            float iou = inter / (ia + sar[j] - inter);      // NaN -> false, matches JAX
            if (iou > IOU_TH) m |= 1ull << (j - j0);
        }
        if (w == 0) m0[i] = m; else if (w == 1) m1[i] = m; else m2[i] = m;
    }
    __syncthreads();

    // serial bitset resolve, unrolled x4 with grouped b128 loads. Fast path: suppression
    // is rare (~40 set bits over 576 words), so most 4-groups have all-zero masks AND
    // clear removed-bits -> keep all 4 at once with no dependent chain. Slow path is the
    // exact per-element recursion. All threads run redundantly in lockstep.
    unsigned long long rem0 = 0, rem1 = 0, rem2 = 0;
    int kept = 0;
    for (int k0 = 0; k0 < nS && kept < MAXD; k0 += 4) {
        ulonglong2 A0 = *(const ulonglong2*)&m0[k0];
        ulonglong2 A1 = *(const ulonglong2*)&m0[k0 + 2];
        ulonglong2 B0 = *(const ulonglong2*)&m1[k0];
        ulonglong2 B1 = *(const ulonglong2*)&m1[k0 + 2];
        ulonglong2 C0 = *(const ulonglong2*)&m2[k0];
        ulonglong2 C1 = *(const ulonglong2*)&m2[k0 + 2];
        // clean-block fast path: (k0&63)<=60 always (k0%4==0), so 4 rem bits share a word
        unsigned long long g = A0.x | A0.y | A1.x | A1.y | B0.x | B0.y | B1.x | B1.y
                             | C0.x | C0.y | C1.x | C1.y;
        unsigned long long rw4 = ((k0 < 64) ? rem0 : (k0 < 128) ? rem1 : rem2) >> (k0 & 63);
        if (g == 0ull && (rw4 & 0xFull) == 0ull && k0 + 4 <= nS && kept + 4 <= MAXD) {
            if (threadIdx.x == 0) {
                kidx[kept] = k0; kidx[kept + 1] = k0 + 1;
                kidx[kept + 2] = k0 + 2; kidx[kept + 3] = k0 + 3;
            }
            kept += 4;
            continue;
        }
        #pragma unroll
        for (int s = 0; s < 4; ++s) {
            int k = k0 + s;
            if (k < nS && kept < MAXD) {
                unsigned long long mm0 = (s == 0) ? A0.x : (s == 1) ? A0.y : (s == 2) ? A1.x : A1.y;
                unsigned long long mm1 = (s == 0) ? B0.x : (s == 1) ? B0.y : (s == 2) ? B1.x : B1.y;
                unsigned long long mm2 = (s == 0) ? C0.x : (s == 1) ? C0.y : (s == 2) ? C1.x : C1.y;
                unsigned long long rw = (k < 64) ? rem0 : (k < 128) ? rem1 : rem2;
                if (!((rw >> (k & 63)) & 1ull)) {
                    if (threadIdx.x == 0) kidx[kept] = k;
                    ++kept;
                    rem0 |= mm0; rem1 |= mm1; rem2 |= mm2;
                }
            }
        }
    }
    __syncthreads();   // kidx visible

    if (kept < MAXD && (n > nS || loflag[c] != 0)) {   // unexamined candidates may exist
        fallback_class(cls, anch, reg, W, H, A, C, c, out);
        return;
    }

    int total = C * MAXD;
    int base = c * MAXD;
    for (int m = threadIdx.x; m < kept; m += blockDim.x) {
        int k = kidx[m];
        unsigned long long key = keys[k];
        float sc = __uint_as_float(~(unsigned)(key >> 32));
        out[base + m] = sc;
        out[total + base + m] = (float)c;
        float* ob = out + 2 * (size_t)total + (size_t)(base + m) * 4;
        ob[0] = bx1[k]; ob[1] = by1[k]; ob[2] = bx2[k]; ob[3] = by2[k];
    }
    for (int m = kept + threadIdx.x; m < MAXD; m += blockDim.x) {
        out[base + m] = 0.f;
        out[total + base + m] = -1.f;
        float* ob = out + 2 * (size_t)total + (size_t)(base + m) * 4;
        ob[0] = 0.f; ob[1] = 0.f; ob[2] = 0.f; ob[3] = 0.f;
    }
}

extern "C" void kernel_launch(void* const* d_in, const int* in_sizes, int n_in,
                              void* d_out, int out_size, void* d_ws, size_t ws_size,
                              hipStream_t stream)
{
    const float*  cls  = (const float*)d_in[0];
    const float4* reg  = (const float4*)d_in[1];
    const float4* anch = (const float4*)d_in[2];
    const int*    ph   = (const int*)d_in[3];
    const int*    pw   = (const int*)d_in[4];
    int A = in_sizes[1] / 4;
    int C = in_sizes[0] / A;
    float* out = (float*)d_out;

    char* ws = (char*)d_ws;
    float2* cand = (float2*)ws;                        // C*CAP * 8B
    int* ctrl   = (int*)(cand + (size_t)C * CAP);      // cnt_pad[C*16] | loflag[C]
    int* cnt    = ctrl;                                // strided by CNT_STRIDE
    int* loflag = ctrl + C * CNT_STRIDE;

    hipMemsetAsync(ctrl, 0, (C * CNT_STRIDE + C) * sizeof(int), stream);

    int total4 = (int)((long long)A * C / 4);
    int blocks2 = (total4 + 255) / 256;
    if (blocks2 > 2048) blocks2 = 2048;
    if (C == 80 && (long long)A * C < (1LL << 31))
        k_compact<80><<<blocks2, 256, 0, stream>>>((const float4*)cls, cand, cnt, loflag, C, total4);
    else
        k_compact<0><<<blocks2, 256, 0, stream>>>((const float4*)cls, cand, cnt, loflag, C, total4);

    k_nms<<<C, 256, 0, stream>>>(cls, anch, reg, ph, pw, cand, cnt, loflag, out, A, C);
}

// Round 12
// 136.155 us; speedup vs baseline: 1.0716x; 1.0304x over previous
//
#include <hip/hip_runtime.h>
#include <float.h>
#include <math.h>

#define SCORE_TH 0.05f
#define IOU_TH   0.5f
#define MAXD     100
#define CAP      512       // per-class candidate buffer (E[n]=200, sigma=14 -> 22 sigma margin)
#define HI_TH    0.996f    // P(uniform^4 > 0.996) ~ 1.0e-3 -> ~200 cand/class
#define SWALK    192       // sorted prefix examined (multiple of 4; need ~110 to keep 100)
#define NWORDS   3
#define CNT_STRIDE 16      // pad class counters to one 64B line each (atomic line-parallelism)

// Inline RetinaNet decode + clip (identical arithmetic to the originally verified k_decode)
__device__ __forceinline__ float4 decode_box(float4 an, float4 r, float W, float H)
{
    float wa = an.z - an.x, ha = an.w - an.y;
    float cxa = an.x + 0.5f * wa, cya = an.y + 0.5f * ha;
    float cx = cxa + r.x * 0.1f * wa;
    float cy = cya + r.y * 0.1f * ha;
    float w  = expf(r.z * 0.2f) * wa;
    float h  = expf(r.w * 0.2f) * ha;
    float x1 = cx - 0.5f * w, y1 = cy - 0.5f * h;
    float x2 = cx + 0.5f * w, y2 = cy + 0.5f * h;
    x1 = fminf(fmaxf(x1, 0.f), W);
    y1 = fminf(fmaxf(y1, 0.f), H);
    x2 = fminf(fmaxf(x2, 0.f), W);
    y2 = fminf(fmaxf(y2, 0.f), H);
    return make_float4(x1, y1, x2, y2);
}

// ---------------- K2: grid-stride candidate compaction (verified; unchanged) ----------------
template<int CC>
__global__ __launch_bounds__(256)
void k_compact(const float4* __restrict__ cls4, float2* __restrict__ cand,
               int* __restrict__ cnt, int* __restrict__ loflag,
               int C_rt, int total4)
{
    const int C = CC ? CC : C_rt;
    __shared__ unsigned char lflag[256];   // C <= 256 assumed (C=80 here)
    for (int i = threadIdx.x; i < C; i += blockDim.x) lflag[i] = 0;
    __syncthreads();

    const int gstride = gridDim.x * blockDim.x;
    const int gtid = blockIdx.x * blockDim.x + threadIdx.x;

    for (int j0 = gtid; j0 < total4; j0 += 4 * gstride) {
        int j1 = j0 + gstride, j2 = j0 + 2 * gstride, j3 = j0 + 3 * gstride;
        bool ok1 = j1 < total4, ok2 = j2 < total4, ok3 = j3 < total4;
        float4 v0 = cls4[j0];
        float4 v1 = ok1 ? cls4[j1] : make_float4(0.f, 0.f, 0.f, 0.f);
        float4 v2 = ok2 ? cls4[j2] : make_float4(0.f, 0.f, 0.f, 0.f);
        float4 v3 = ok3 ? cls4[j3] : make_float4(0.f, 0.f, 0.f, 0.f);

        #pragma unroll
        for (int w = 0; w < 4; w++) {
            float4 v = (w == 0) ? v0 : (w == 1) ? v1 : (w == 2) ? v2 : v3;
            if (w == 1 && !ok1) break;
            if (w == 2 && !ok2) break;
            if (w == 3 && !ok3) break;
            unsigned b = (unsigned)(j0 + w * gstride) * 4u;   // flat element index (<2^31)
            int c = (int)(b % (unsigned)C);
            int a = (int)(b / (unsigned)C);
            float s[4] = {v.x, v.y, v.z, v.w};
            #pragma unroll
            for (int j = 0; j < 4; j++) {
                float sc = s[j];
                if (sc > HI_TH) {
                    int pos = atomicAdd(&cnt[c * CNT_STRIDE], 1);
                    if (pos < CAP) cand[(size_t)c * CAP + pos] = make_float2(sc, __int_as_float(a));
                } else if (sc > SCORE_TH) {
                    lflag[c] = 1;
                }
                c++; if (c == C) { c = 0; a++; }
            }
        }
    }
    __syncthreads();
    for (int i = threadIdx.x; i < C; i += blockDim.x)
        if (lflag[i]) loflag[i] = 1;
}

// ---------------- inline exact fallback (lazy sorted-order walk over all A) ----------------
__device__ void fallback_class(const float* __restrict__ cls,
                               const float4* __restrict__ anch, const float4* __restrict__ reg,
                               float W, float H, int A, int C, int c,
                               float* __restrict__ out)
{
    __shared__ float kx1[MAXD], ky1[MAXD], kx2[MAXD], ky2[MAXD], kar[MAXD];
    __shared__ float rs[4]; __shared__ int ra[4];
    __shared__ float cs; __shared__ int caid; __shared__ int have; __shared__ int suppflag;
    int lane = threadIdx.x & 63, wid = threadIdx.x >> 6;
    float s_last = FLT_MAX; int a_last = -1;
    int kept = 0;
    int total = C * MAXD;
    for (long long guard = 0; guard <= (long long)A && kept < MAXD; guard++) {
        float bs = -1.f; int ba = 0x7fffffff;
        for (int a = threadIdx.x; a < A; a += blockDim.x) {
            float s = cls[(size_t)a * C + c];
            if (s <= SCORE_TH) continue;
            if (s > s_last || (s == s_last && a <= a_last)) continue;  // already examined
            if (s > bs || (s == bs && a < ba)) { bs = s; ba = a; }
        }
        for (int off = 32; off >= 1; off >>= 1) {
            float s2 = __shfl_down(bs, off);
            int a2 = __shfl_down(ba, off);
            if (s2 > bs || (s2 == bs && a2 < ba)) { bs = s2; ba = a2; }
        }
        if (lane == 0) { rs[wid] = bs; ra[wid] = ba; }
        __syncthreads();
        if (threadIdx.x == 0) {
            float fs = rs[0]; int fa = ra[0];
            for (int w = 1; w < 4; w++)
                if (rs[w] > fs || (rs[w] == fs && ra[w] < fa)) { fs = rs[w]; fa = ra[w]; }
            cs = fs; caid = fa; have = (fs > 0.f) ? 1 : 0;
        }
        __syncthreads();
        if (!have) break;
        float s_c = cs; int a_c = caid;
        s_last = s_c; a_last = a_c;
        float4 b = decode_box(anch[a_c], reg[a_c], W, H);
        float ar = (b.z - b.x) * (b.w - b.y);
        if (threadIdx.x == 0) suppflag = 0;
        __syncthreads();
        for (int k = threadIdx.x; k < kept; k += blockDim.x) {
            float xx1 = fmaxf(b.x, kx1[k]);
            float yy1 = fmaxf(b.y, ky1[k]);
            float xx2 = fminf(b.z, kx2[k]);
            float yy2 = fminf(b.w, ky2[k]);
            float inter = fmaxf(xx2 - xx1, 0.f) * fmaxf(yy2 - yy1, 0.f);
            float iou = inter / (ar + kar[k] - inter);
            if (iou > IOU_TH) suppflag = 1;  // racy idempotent
        }
        __syncthreads();
        if (!suppflag) {
            if (threadIdx.x == 0) {
                kx1[kept] = b.x; ky1[kept] = b.y; kx2[kept] = b.z; ky2[kept] = b.w; kar[kept] = ar;
                int slot = c * MAXD + kept;
                out[slot] = s_c;
                out[total + slot] = (float)c;
                float* ob = out + 2 * (size_t)total + (size_t)slot * 4;
                ob[0] = b.x; ob[1] = b.y; ob[2] = b.z; ob[3] = b.w;
            }
            kept++;
        }
        __syncthreads();
    }
    for (int k = kept + threadIdx.x; k < MAXD; k += blockDim.x) {
        int slot = c * MAXD + k;
        out[slot] = 0.f;
        out[total + slot] = -1.f;
        float* ob = out + 2 * (size_t)total + (size_t)slot * 4;
        ob[0] = 0.f; ob[1] = 0.f; ob[2] = 0.f; ob[3] = 0.f;
    }
}

// ---------------- K3: rank-scatter sort + parallel mask + pipelined resolve ----------------
__global__ __launch_bounds__(256)
void k_nms(const float* __restrict__ cls,
           const float4* __restrict__ anch, const float4* __restrict__ reg,
           const int* __restrict__ ph, const int* __restrict__ pw,
           const float2* __restrict__ cand, const int* __restrict__ cnt,
           const int* __restrict__ loflag,
           float* __restrict__ out, int A, int C)
{
    int c = blockIdx.x;
    __shared__ __align__(16) unsigned long long keys_raw[CAP];
    __shared__ unsigned long long keys[SWALK];     // rank-scattered: ascending = best first
    __shared__ float bx1[SWALK], by1[SWALK], bx2[SWALK], by2[SWALK], sar[SWALK];
    __shared__ __align__(16) unsigned long long m0[SWALK], m1[SWALK], m2[SWALK];
    __shared__ int kidx[MAXD];

    float W = (float)(*pw), H = (float)(*ph);
    int n_raw = cnt[c * CNT_STRIDE];
    if (n_raw > CAP) {                   // lost candidates -> exact fallback, inline
        fallback_class(cls, anch, reg, W, H, A, C, c, out);
        return;
    }
    int n = n_raw;
    int nS = n < SWALK ? n : SWALK;

    // build raw keys: ascending key == descending score, tie -> ascending anchor id
    for (int i = threadIdx.x; i < n; i += blockDim.x) {
        float2 e = cand[(size_t)c * CAP + i];
        unsigned sbits = __float_as_uint(e.x);          // score > 0 -> bits monotone
        unsigned aid   = (unsigned)__float_as_int(e.y); // anchor id
        keys_raw[i] = ((unsigned long long)(~sbits) << 32) | (unsigned long long)aid;
    }
    __syncthreads();

    // rank-scatter sort: keys unique -> rank = exact sorted position (1 barrier vs 36).
    // Broadcast-friendly LDS reads; scatter key AND decoded box directly to rank slot.
    for (int i = threadIdx.x; i < n; i += blockDim.x) {
        unsigned long long ki = keys_raw[i];
        int r = 0;
        int j = 0;
        for (; j + 2 <= n; j += 2) {
            ulonglong2 kj = *(const ulonglong2*)&keys_raw[j];   // j even, 16B-aligned
            r += (kj.x < ki) + (kj.y < ki);
        }
        if (j < n) r += (keys_raw[j] < ki);
        if (r < SWALK) {
            keys[r] = ki;
            unsigned aid = (unsigned)ki;
            float4 b = decode_box(anch[aid], reg[aid], W, H);
            bx1[r] = b.x; by1[r] = b.y; bx2[r] = b.z; by2[r] = b.w;
            sar[r] = (b.z - b.x) * (b.w - b.y);
        }
    }
    __syncthreads();

    // parallel suppression-mask build: task=(row i, word w); bit j (>i) set if IoU>th
    for (int task = threadIdx.x; task < nS * NWORDS; task += blockDim.x) {
        int i = task / NWORDS;
        int w = task - i * NWORDS;
        unsigned long long m = 0ull;
        int j0 = w << 6;
        int jend = j0 + 64 < nS ? j0 + 64 : nS;
        int js = j0 > i + 1 ? j0 : i + 1;
        float ix1 = bx1[i], iy1 = by1[i], ix2 = bx2[i], iy2 = by2[i], ia = sar[i];
        for (int j = js; j < jend; ++j) {
            float xx1 = fmaxf(ix1, bx1[j]);
            float yy1 = fmaxf(iy1, by1[j]);
            float xx2 = fminf(ix2, bx2[j]);
            float yy2 = fminf(iy2, by2[j]);
            float inter = fmaxf(xx2 - xx1, 0.f) * fmaxf(yy2 - yy1, 0.f);
            float iou = inter / (ia + sar[j] - inter);      // NaN -> false, matches JAX
            if (iou > IOU_TH) m |= 1ull << (j - j0);
        }
        if (w == 0) m0[i] = m; else if (w == 1) m1[i] = m; else m2[i] = m;
    }
    __syncthreads();

    // serial bitset resolve, x4-unrolled, software-pipelined: load group g+1 while
    // resolving group g (hides LDS latency under the OR/branch ALU). Fast path keeps a
    // whole clean 4-group at once. All threads redundant in lockstep; exact recursion.
    unsigned long long rem0 = 0, rem1 = 0, rem2 = 0;
    int kept = 0;
    ulonglong2 A0 = *(const ulonglong2*)&m0[0], A1 = *(const ulonglong2*)&m0[2];
    ulonglong2 B0 = *(const ulonglong2*)&m1[0], B1 = *(const ulonglong2*)&m1[2];
    ulonglong2 Q0 = *(const ulonglong2*)&m2[0], Q1 = *(const ulonglong2*)&m2[2];
    for (int k0 = 0; k0 < nS && kept < MAXD; k0 += 4) {
        ulonglong2 nA0, nA1, nB0, nB1, nQ0, nQ1;
        int kn = k0 + 4;
        if (kn < nS) {                                   // prefetch next group
            nA0 = *(const ulonglong2*)&m0[kn]; nA1 = *(const ulonglong2*)&m0[kn + 2];
            nB0 = *(const ulonglong2*)&m1[kn]; nB1 = *(const ulonglong2*)&m1[kn + 2];
            nQ0 = *(const ulonglong2*)&m2[kn]; nQ1 = *(const ulonglong2*)&m2[kn + 2];
        }
        unsigned long long g = A0.x | A0.y | A1.x | A1.y | B0.x | B0.y | B1.x | B1.y
                             | Q0.x | Q0.y | Q1.x | Q1.y;
        unsigned long long rw4 = ((k0 < 64) ? rem0 : (k0 < 128) ? rem1 : rem2) >> (k0 & 63);
        if (g == 0ull && (rw4 & 0xFull) == 0ull && k0 + 4 <= nS && kept + 4 <= MAXD) {
            if (threadIdx.x == 0) {
                kidx[kept] = k0; kidx[kept + 1] = k0 + 1;
                kidx[kept + 2] = k0 + 2; kidx[kept + 3] = k0 + 3;
            }
            kept += 4;
        } else {
            #pragma unroll
            for (int s = 0; s < 4; ++s) {
                int k = k0 + s;
                if (k < nS && kept < MAXD) {
                    unsigned long long mm0 = (s == 0) ? A0.x : (s == 1) ? A0.y : (s == 2) ? A1.x : A1.y;
                    unsigned long long mm1 = (s == 0) ? B0.x : (s == 1) ? B0.y : (s == 2) ? B1.x : B1.y;
                    unsigned long long mm2 = (s == 0) ? Q0.x : (s == 1) ? Q0.y : (s == 2) ? Q1.x : Q1.y;
                    unsigned long long rw = (k < 64) ? rem0 : (k < 128) ? rem1 : rem2;
                    if (!((rw >> (k & 63)) & 1ull)) {
                        if (threadIdx.x == 0) kidx[kept] = k;
                        ++kept;
                        rem0 |= mm0; rem1 |= mm1; rem2 |= mm2;
                    }
                }
            }
        }
        A0 = nA0; A1 = nA1; B0 = nB0; B1 = nB1; Q0 = nQ0; Q1 = nQ1;
    }
    __syncthreads();   // kidx visible

    if (kept < MAXD && (n > nS || loflag[c] != 0)) {   // unexamined candidates may exist
        fallback_class(cls, anch, reg, W, H, A, C, c, out);
        return;
    }

    int total = C * MAXD;
    int base = c * MAXD;
    for (int m = threadIdx.x; m < kept; m += blockDim.x) {
        int k = kidx[m];
        unsigned long long key = keys[k];
        float sc = __uint_as_float(~(unsigned)(key >> 32));
        out[base + m] = sc;
        out[total + base + m] = (float)c;
        float* ob = out + 2 * (size_t)total + (size_t)(base + m) * 4;
        ob[0] = bx1[k]; ob[1] = by1[k]; ob[2] = bx2[k]; ob[3] = by2[k];
    }
    for (int m = kept + threadIdx.x; m < MAXD; m += blockDim.x) {
        out[base + m] = 0.f;
        out[total + base + m] = -1.f;
        float* ob = out + 2 * (size_t)total + (size_t)(base + m) * 4;
        ob[0] = 0.f; ob[1] = 0.f; ob[2] = 0.f; ob[3] = 0.f;
    }
}

extern "C" void kernel_launch(void* const* d_in, const int* in_sizes, int n_in,
                              void* d_out, int out_size, void* d_ws, size_t ws_size,
                              hipStream_t stream)
{
    const float*  cls  = (const float*)d_in[0];
    const float4* reg  = (const float4*)d_in[1];
    const float4* anch = (const float4*)d_in[2];
    const int*    ph   = (const int*)d_in[3];
    const int*    pw   = (const int*)d_in[4];
    int A = in_sizes[1] / 4;
    int C = in_sizes[0] / A;
    float* out = (float*)d_out;

    char* ws = (char*)d_ws;
    float2* cand = (float2*)ws;                        // C*CAP * 8B
    int* ctrl   = (int*)(cand + (size_t)C * CAP);      // cnt_pad[C*16] | loflag[C]
    int* cnt    = ctrl;                                // strided by CNT_STRIDE
    int* loflag = ctrl + C * CNT_STRIDE;

    hipMemsetAsync(ctrl, 0, (C * CNT_STRIDE + C) * sizeof(int), stream);

    int total4 = (int)((long long)A * C / 4);
    int blocks2 = (total4 + 255) / 256;
    if (blocks2 > 2048) blocks2 = 2048;
    if (C == 80 && (long long)A * C < (1LL << 31))
        k_compact<80><<<blocks2, 256, 0, stream>>>((const float4*)cls, cand, cnt, loflag, C, total4);
    else
        k_compact<0><<<blocks2, 256, 0, stream>>>((const float4*)cls, cand, cnt, loflag, C, total4);

    k_nms<<<C, 256, 0, stream>>>(cls, anch, reg, ph, pw, cand, cnt, loflag, out, A, C);
}

// Round 13
// 128.085 us; speedup vs baseline: 1.1392x; 1.0630x over previous
//
#include <hip/hip_runtime.h>
#include <float.h>
#include <math.h>

#define SCORE_TH 0.05f
#define IOU_TH   0.5f
#define MAXD     100
#define CAP      512       // per-class candidate buffer (E[n]=200, sigma=14 -> 22 sigma margin)
#define HI_TH    0.996f    // P(uniform^4 > 0.996) ~ 1.0e-3 -> ~200 cand/class
#define SWALK    192       // sorted prefix examined (need ~110 to keep 100); 3 u64 words
#define NWORDS   3
#define CNT_STRIDE 16      // pad class counters to one 64B line each (atomic line-parallelism)

// Inline RetinaNet decode + clip (identical arithmetic across all uses -> identical bits)
__device__ __forceinline__ float4 decode_box(float4 an, float4 r, float W, float H)
{
    float wa = an.z - an.x, ha = an.w - an.y;
    float cxa = an.x + 0.5f * wa, cya = an.y + 0.5f * ha;
    float cx = cxa + r.x * 0.1f * wa;
    float cy = cya + r.y * 0.1f * ha;
    float w  = expf(r.z * 0.2f) * wa;
    float h  = expf(r.w * 0.2f) * ha;
    float x1 = cx - 0.5f * w, y1 = cy - 0.5f * h;
    float x2 = cx + 0.5f * w, y2 = cy + 0.5f * h;
    x1 = fminf(fmaxf(x1, 0.f), W);
    y1 = fminf(fmaxf(y1, 0.f), H);
    x2 = fminf(fmaxf(x2, 0.f), W);
    y2 = fminf(fmaxf(y2, 0.f), H);
    return make_float4(x1, y1, x2, y2);
}

struct CandRec { float4 a; float4 b; };  // a=(score, aid_bits, x1, y1) b=(x2, y2, area, 0)

// ---------------- K2: grid-stride compaction + hit-path decode (main loop unchanged) ----------------
template<int CC>
__global__ __launch_bounds__(256)
void k_compact(const float4* __restrict__ cls4,
               const float4* __restrict__ anch, const float4* __restrict__ reg,
               const int* __restrict__ ph, const int* __restrict__ pw,
               CandRec* __restrict__ cand,
               int* __restrict__ cnt, int* __restrict__ loflag,
               int C_rt, int total4)
{
    const int C = CC ? CC : C_rt;
    __shared__ unsigned char lflag[256];   // C <= 256 assumed (C=80 here)
    for (int i = threadIdx.x; i < C; i += blockDim.x) lflag[i] = 0;
    __syncthreads();

    float W = (float)(*pw), H = (float)(*ph);
    const int gstride = gridDim.x * blockDim.x;
    const int gtid = blockIdx.x * blockDim.x + threadIdx.x;

    for (int j0 = gtid; j0 < total4; j0 += 4 * gstride) {
        int j1 = j0 + gstride, j2 = j0 + 2 * gstride, j3 = j0 + 3 * gstride;
        bool ok1 = j1 < total4, ok2 = j2 < total4, ok3 = j3 < total4;
        float4 v0 = cls4[j0];
        float4 v1 = ok1 ? cls4[j1] : make_float4(0.f, 0.f, 0.f, 0.f);
        float4 v2 = ok2 ? cls4[j2] : make_float4(0.f, 0.f, 0.f, 0.f);
        float4 v3 = ok3 ? cls4[j3] : make_float4(0.f, 0.f, 0.f, 0.f);

        #pragma unroll
        for (int w = 0; w < 4; w++) {
            float4 v = (w == 0) ? v0 : (w == 1) ? v1 : (w == 2) ? v2 : v3;
            if (w == 1 && !ok1) break;
            if (w == 2 && !ok2) break;
            if (w == 3 && !ok3) break;
            unsigned b = (unsigned)(j0 + w * gstride) * 4u;   // flat element index (<2^31)
            int c = (int)(b % (unsigned)C);
            int a = (int)(b / (unsigned)C);
            float s[4] = {v.x, v.y, v.z, v.w};
            #pragma unroll
            for (int j = 0; j < 4; j++) {
                float sc = s[j];
                if (sc > HI_TH) {
                    int pos = atomicAdd(&cnt[c * CNT_STRIDE], 1);
                    if (pos < CAP) {
                        float4 bx = decode_box(anch[a], reg[a], W, H);   // rare path (~0.1%)
                        float area = (bx.z - bx.x) * (bx.w - bx.y);
                        CandRec* r = &cand[(size_t)c * CAP + pos];
                        r->a = make_float4(sc, __int_as_float(a), bx.x, bx.y);
                        r->b = make_float4(bx.z, bx.w, area, 0.f);
                    }
                } else if (sc > SCORE_TH) {
                    lflag[c] = 1;
                }
                c++; if (c == C) { c = 0; a++; }
            }
        }
    }
    __syncthreads();
    for (int i = threadIdx.x; i < C; i += blockDim.x)
        if (lflag[i]) loflag[i] = 1;
}

// ---------------- inline exact fallback (lazy sorted-order walk over all A; unchanged) ----------------
__device__ void fallback_class(const float* __restrict__ cls,
                               const float4* __restrict__ anch, const float4* __restrict__ reg,
                               float W, float H, int A, int C, int c,
                               float* __restrict__ out)
{
    __shared__ float kx1[MAXD], ky1[MAXD], kx2[MAXD], ky2[MAXD], kar[MAXD];
    __shared__ float rs[4]; __shared__ int ra[4];
    __shared__ float cs; __shared__ int caid; __shared__ int have; __shared__ int suppflag;
    int lane = threadIdx.x & 63, wid = threadIdx.x >> 6;
    float s_last = FLT_MAX; int a_last = -1;
    int kept = 0;
    int total = C * MAXD;
    for (long long guard = 0; guard <= (long long)A && kept < MAXD; guard++) {
        float bs = -1.f; int ba = 0x7fffffff;
        for (int a = threadIdx.x; a < A; a += blockDim.x) {
            float s = cls[(size_t)a * C + c];
            if (s <= SCORE_TH) continue;
            if (s > s_last || (s == s_last && a <= a_last)) continue;  // already examined
            if (s > bs || (s == bs && a < ba)) { bs = s; ba = a; }
        }
        for (int off = 32; off >= 1; off >>= 1) {
            float s2 = __shfl_down(bs, off);
            int a2 = __shfl_down(ba, off);
            if (s2 > bs || (s2 == bs && a2 < ba)) { bs = s2; ba = a2; }
        }
        if (lane == 0) { rs[wid] = bs; ra[wid] = ba; }
        __syncthreads();
        if (threadIdx.x == 0) {
            float fs = rs[0]; int fa = ra[0];
            for (int w = 1; w < 4; w++)
                if (rs[w] > fs || (rs[w] == fs && ra[w] < fa)) { fs = rs[w]; fa = ra[w]; }
            cs = fs; caid = fa; have = (fs > 0.f) ? 1 : 0;
        }
        __syncthreads();
        if (!have) break;
        float s_c = cs; int a_c = caid;
        s_last = s_c; a_last = a_c;
        float4 b = decode_box(anch[a_c], reg[a_c], W, H);
        float ar = (b.z - b.x) * (b.w - b.y);
        if (threadIdx.x == 0) suppflag = 0;
        __syncthreads();
        for (int k = threadIdx.x; k < kept; k += blockDim.x) {
            float xx1 = fmaxf(b.x, kx1[k]);
            float yy1 = fmaxf(b.y, ky1[k]);
            float xx2 = fminf(b.z, kx2[k]);
            float yy2 = fminf(b.w, ky2[k]);
            float inter = fmaxf(xx2 - xx1, 0.f) * fmaxf(yy2 - yy1, 0.f);
            float iou = inter / (ar + kar[k] - inter);
            if (iou > IOU_TH) suppflag = 1;  // racy idempotent
        }
        __syncthreads();
        if (!suppflag) {
            if (threadIdx.x == 0) {
                kx1[kept] = b.x; ky1[kept] = b.y; kx2[kept] = b.z; ky2[kept] = b.w; kar[kept] = ar;
                int slot = c * MAXD + kept;
                out[slot] = s_c;
                out[total + slot] = (float)c;
                float* ob = out + 2 * (size_t)total + (size_t)slot * 4;
                ob[0] = b.x; ob[1] = b.y; ob[2] = b.z; ob[3] = b.w;
            }
            kept++;
        }
        __syncthreads();
    }
    for (int k = kept + threadIdx.x; k < MAXD; k += blockDim.x) {
        int slot = c * MAXD + k;
        out[slot] = 0.f;
        out[total + slot] = -1.f;
        float* ob = out + 2 * (size_t)total + (size_t)slot * 4;
        ob[0] = 0.f; ob[1] = 0.f; ob[2] = 0.f; ob[3] = 0.f;
    }
}

// ---------------- K3: rank-scatter + transposed mask + parallel fixpoint resolve ----------------
// Exactness: F(S)={k: no i<k in S with IoU>th} has a UNIQUE fixpoint = greedy-kept
// (induction on first differing index); iteration kw0 ⊇ greedy ⊇ kw1 ⊆ kw2 ... converges,
// stop on kw unchanged. MAXD truncation = first 100 kept in sorted order (greedy prefix
// property). Shortfall with unexamined candidates -> exact fallback.
__global__ __launch_bounds__(256)
void k_nms(const float* __restrict__ cls,
           const float4* __restrict__ anch, const float4* __restrict__ reg,
           const int* __restrict__ ph, const int* __restrict__ pw,
           const CandRec* __restrict__ cand, const int* __restrict__ cnt,
           const int* __restrict__ loflag,
           float* __restrict__ out, int A, int C)
{
    int c = blockIdx.x;
    __shared__ __align__(16) unsigned long long keys_raw[CAP];
    __shared__ float4 box_u[CAP];
    __shared__ float  sar_u[CAP];
    __shared__ unsigned long long keys[SWALK];     // rank-scattered: ascending = best first
    __shared__ float4 box[SWALK];
    __shared__ float  sar[SWALK];
    __shared__ unsigned long long t0[SWALK], t1[SWALK], t2[SWALK]; // maskT planes: bit i<k of col k
    __shared__ unsigned long long kw[NWORDS], newkw[NWORDS];
    __shared__ int changed;

    float W = (float)(*pw), H = (float)(*ph);
    int tid = threadIdx.x;
    int n_raw = cnt[c * CNT_STRIDE];
    if (n_raw > CAP) {                   // lost candidates -> exact fallback, inline
        fallback_class(cls, anch, reg, W, H, A, C, c, out);
        return;
    }
    int n = n_raw;
    int nS = n < SWALK ? n : SWALK;

    // load records (single HBM round; boxes pre-decoded by k_compact)
    for (int i = tid; i < n; i += blockDim.x) {
        CandRec rec = cand[(size_t)c * CAP + i];
        unsigned sbits = __float_as_uint(rec.a.x);
        unsigned aid   = (unsigned)__float_as_int(rec.a.y);
        keys_raw[i] = ((unsigned long long)(~sbits) << 32) | (unsigned long long)aid;
        box_u[i] = make_float4(rec.a.z, rec.a.w, rec.b.x, rec.b.y);
        sar_u[i] = rec.b.z;
    }
    __syncthreads();

    // rank-scatter sort (keys unique -> rank = exact position; broadcast LDS reads)
    for (int i = tid; i < n; i += blockDim.x) {
        unsigned long long ki = keys_raw[i];
        int r = 0;
        int j = 0;
        for (; j + 2 <= n; j += 2) {
            ulonglong2 kj = *(const ulonglong2*)&keys_raw[j];
            r += (kj.x < ki) + (kj.y < ki);
        }
        if (j < n) r += (keys_raw[j] < ki);
        if (r < SWALK) {
            keys[r] = ki;
            box[r] = box_u[i];
            sar[r] = sar_u[i];
        }
    }
    __syncthreads();

    // transposed mask build: task=(col k, word w); bit i in [64w,64w+64) ∩ [0,k)
    for (int task = tid; task < nS * NWORDS; task += blockDim.x) {
        int k = task / NWORDS;
        int w = task - k * NWORDS;
        unsigned long long m = 0ull;
        int i0 = w << 6;
        int iend = (i0 + 64 < k) ? (i0 + 64) : k;
        if (i0 < iend) {
            float4 bk = box[k]; float ak = sar[k];
            for (int i = i0; i < iend; ++i) {
                float4 bi = box[i];                         // one b128 LDS read
                float xx1 = fmaxf(bk.x, bi.x);
                float yy1 = fmaxf(bk.y, bi.y);
                float xx2 = fminf(bk.z, bi.z);
                float yy2 = fminf(bk.w, bi.w);
                float inter = fmaxf(xx2 - xx1, 0.f) * fmaxf(yy2 - yy1, 0.f);
                float iou = inter / (ak + sar[i] - inter);  // NaN -> false, matches JAX
                if (iou > IOU_TH) m |= 1ull << (i - i0);
            }
        }
        if (w == 0) t0[k] = m; else if (w == 1) t1[k] = m; else t2[k] = m;
    }
    if (tid == 0) {
        kw[0] = (nS >= 64) ? ~0ull : ((nS <= 0) ? 0ull : ((1ull << nS) - 1));
        int r1 = nS - 64;
        kw[1] = (r1 >= 64) ? ~0ull : ((r1 <= 0) ? 0ull : ((1ull << r1) - 1));
        int r2 = nS - 128;
        kw[2] = (r2 >= 64) ? ~0ull : ((r2 <= 0) ? 0ull : ((1ull << r2) - 1));
    }
    __syncthreads();

    // parallel fixpoint resolve (typ. 2-3 iterations; hard cap nS+1)
    for (int iter = 0; iter <= nS; ++iter) {
        bool kept_k = false;
        if (tid < nS) {
            unsigned long long r = (t0[tid] & kw[0]) | (t1[tid] & kw[1]) | (t2[tid] & kw[2]);
            kept_k = (r == 0ull);
        }
        unsigned long long b = __ballot(kept_k);
        if ((tid & 63) == 0 && (tid >> 6) < NWORDS) newkw[tid >> 6] = b;
        __syncthreads();
        if (tid == 0) {
            changed = (newkw[0] != kw[0]) || (newkw[1] != kw[1]) || (newkw[2] != kw[2]);
            kw[0] = newkw[0]; kw[1] = newkw[1]; kw[2] = newkw[2];
        }
        __syncthreads();
        if (!changed) break;
    }

    unsigned long long k0r = kw[0], k1r = kw[1], k2r = kw[2];
    int kept_total = __popcll(k0r) + __popcll(k1r) + __popcll(k2r);

    if (kept_total < MAXD && (n > nS || loflag[c] != 0)) {   // unexamined candidates may exist
        __syncthreads();                                     // uniform: all threads took same branch
        fallback_class(cls, anch, reg, W, H, A, C, c, out);
        return;
    }

    int total = C * MAXD;
    int base = c * MAXD;
    // parallel output: thread k writes its kept candidate at its popcount-prefix position
    if (tid < nS) {
        int k = tid;
        unsigned long long myw = (k < 64) ? k0r : (k < 128) ? k1r : k2r;
        if ((myw >> (k & 63)) & 1ull) {
            int pos = 0;
            if (k >= 64)  pos += __popcll(k0r);
            if (k >= 128) pos += __popcll(k1r);
            pos += __popcll(myw & ((1ull << (k & 63)) - 1ull));
            if (pos < MAXD) {
                unsigned long long key = keys[k];
                float sc = __uint_as_float(~(unsigned)(key >> 32));
                out[base + pos] = sc;
                out[total + base + pos] = (float)c;
                float4 bb = box[k];
                float* ob = out + 2 * (size_t)total + (size_t)(base + pos) * 4;
                ob[0] = bb.x; ob[1] = bb.y; ob[2] = bb.z; ob[3] = bb.w;
            }
        }
    }
    int keptN = kept_total < MAXD ? kept_total : MAXD;
    for (int m = keptN + tid; m < MAXD; m += blockDim.x) {
        out[base + m] = 0.f;
        out[total + base + m] = -1.f;
        float* ob = out + 2 * (size_t)total + (size_t)(base + m) * 4;
        ob[0] = 0.f; ob[1] = 0.f; ob[2] = 0.f; ob[3] = 0.f;
    }
}

extern "C" void kernel_launch(void* const* d_in, const int* in_sizes, int n_in,
                              void* d_out, int out_size, void* d_ws, size_t ws_size,
                              hipStream_t stream)
{
    const float*  cls  = (const float*)d_in[0];
    const float4* reg  = (const float4*)d_in[1];
    const float4* anch = (const float4*)d_in[2];
    const int*    ph   = (const int*)d_in[3];
    const int*    pw   = (const int*)d_in[4];
    int A = in_sizes[1] / 4;
    int C = in_sizes[0] / A;
    float* out = (float*)d_out;

    char* ws = (char*)d_ws;
    CandRec* cand = (CandRec*)ws;                      // C*CAP * 32B
    int* ctrl   = (int*)(cand + (size_t)C * CAP);      // cnt_pad[C*16] | loflag[C]
    int* cnt    = ctrl;                                // strided by CNT_STRIDE
    int* loflag = ctrl + C * CNT_STRIDE;

    hipMemsetAsync(ctrl, 0, (C * CNT_STRIDE + C) * sizeof(int), stream);

    int total4 = (int)((long long)A * C / 4);
    int blocks2 = (total4 + 255) / 256;
    if (blocks2 > 2048) blocks2 = 2048;
    if (C == 80 && (long long)A * C < (1LL << 31))
        k_compact<80><<<blocks2, 256, 0, stream>>>((const float4*)cls, anch, reg, ph, pw,
                                                   cand, cnt, loflag, C, total4);
    else
        k_compact<0><<<blocks2, 256, 0, stream>>>((const float4*)cls, anch, reg, ph, pw,
                                                  cand, cnt, loflag, C, total4);

    k_nms<<<C, 256, 0, stream>>>(cls, anch, reg, ph, pw, cand, cnt, loflag, out, A, C);
}